// Round 5
// baseline (561.519 us; speedup 1.0000x reference)
//
#include <hip/hip_runtime.h>
#include <hip/hip_bf16.h>
#include <cstdint>
#include <cstddef>

#define SEQ 512
#define BATCH 256
#define IN_DIM 300
#define HID 256

typedef __attribute__((ext_vector_type(8))) short bf16x8;
typedef __attribute__((ext_vector_type(4))) float f32x4;
typedef __attribute__((ext_vector_type(4))) unsigned int u32x4;

__device__ __forceinline__ unsigned short f2bf(float f) {
  union { float f; unsigned int u; } v; v.f = f;
  unsigned int u = v.u;
  return (unsigned short)((u + 0x7fffu + ((u >> 16) & 1u)) >> 16);  // RNE
}
__device__ __forceinline__ unsigned short f2bf_fast(float f) {
  union { float f; unsigned int u; } v; v.f = f;
  return (unsigned short)((v.u + 0x8000u) >> 16);  // round-half-up, err <= 2^-9 rel
}
__device__ __forceinline__ float bitsf(unsigned int u) {
  union { unsigned int u; float f; } v; v.u = u; return v.f;
}
// HW cvt_pk RNE pack of two f32 -> one dword (low = lo).
__device__ __forceinline__ unsigned int cvtpk(float lo, float hi) {
  union { __hip_bfloat162 h; unsigned int u; } c;
  c.h = __float22bfloat162_rn(make_float2(lo, hi));
  return c.u;
}
__device__ __forceinline__ bf16x8 cvt8(float a0,float a1,float a2,float a3,
                                       float a4,float a5,float a6,float a7) {
  union { __hip_bfloat162 h2[4]; bf16x8 v; } c;
  c.h2[0] = __float22bfloat162_rn(make_float2(a0, a1));
  c.h2[1] = __float22bfloat162_rn(make_float2(a2, a3));
  c.h2[2] = __float22bfloat162_rn(make_float2(a4, a5));
  c.h2[3] = __float22bfloat162_rn(make_float2(a6, a7));
  return c.v;
}
// Raw workgroup barrier with LDS-only drain: does NOT force vmcnt(0), so
// global-load prefetches stay in flight across the barrier (T4 pattern).
// Always executed in block-uniform control flow.
__device__ __forceinline__ void barrier_lgkm() {
  asm volatile("s_waitcnt lgkmcnt(0)" ::: "memory");
  __builtin_amdgcn_s_barrier();
  asm volatile("" ::: "memory");
}

struct F8 { float v[8]; };
// guarded 8-float row load (zero-pad past IN_DIM); fully unrolled -> registers
__device__ __forceinline__ F8 load_x8(const float* __restrict__ xrow, int k0, int ac) {
  F8 r;
  if (k0 + ac + 8 <= IN_DIM) {
    float2 p0 = *(const float2*)(xrow + k0 + ac + 0);
    float2 p1 = *(const float2*)(xrow + k0 + ac + 2);
    float2 p2 = *(const float2*)(xrow + k0 + ac + 4);
    float2 p3 = *(const float2*)(xrow + k0 + ac + 6);
    r.v[0]=p0.x; r.v[1]=p0.y; r.v[2]=p1.x; r.v[3]=p1.y;
    r.v[4]=p2.x; r.v[5]=p2.y; r.v[6]=p3.x; r.v[7]=p3.y;
  } else {
    #pragma unroll
    for (int j = 0; j < 8; ++j)
      r.v[j] = (k0 + ac + j < IN_DIM) ? xrow[k0 + ac + j] : 0.f;
  }
  return r;
}

// ---------------- kernel 0: W_ih fp32 -> bf16, FRAGMENT-MAJOR layout.
// Short index: (((n16*10 + kc)*4 + quad)*16 + l15)*8 + j
//   value = W_ih[n16*16 + l15][kc*32 + quad*8 + j]  (0 if k >= 300)
__global__ __launch_bounds__(256) void conv_wih(const float* __restrict__ w,
                                                unsigned short* __restrict__ w_bf) {
  int idx = blockIdx.x * 256 + threadIdx.x;    // 0..81919
  int j    = idx & 7;
  int l15  = (idx >> 3) & 15;
  int quad = (idx >> 7) & 3;
  int t    = idx >> 9;                         // n16*10 + kc
  int n16  = t / 10;
  int kc   = t - n16 * 10;
  int n = n16 * 16 + l15;
  int k = kc * 32 + quad * 8 + j;
  float v = (k < IN_DIM) ? w[n * IN_DIM + k] : 0.f;
  w_bf[idx] = f2bf(v);
}

// ---------------- kernel 1: xp2 (permuted, bf16) = 2*(x@W_ih^T + b_ih + b_hh)
// (byte-identical to round-3/4 version; will appear in top-5 next round once
// rnn_scan drops below it -> first counter set for this kernel)
__global__ __launch_bounds__(512, 2) void gemm_xp(const float* __restrict__ x,
    const unsigned short* __restrict__ w_bf, const float* __restrict__ b_ih,
    const float* __restrict__ b_hh, unsigned int* __restrict__ xp2)
{
  __shared__ unsigned int a_lds[2][128][20];   // packed bf16 pairs, row stride 80 B
  const int tid  = threadIdx.x;
  const int wave = tid >> 6;
  const int lane = tid & 63;
  const int l15  = lane & 15;
  const int quad = lane >> 4;
  const long m0  = (long)blockIdx.x * 128;

  // B fragments, fragment-major coalesced: n16 = wave*2+nt
  bf16x8 wf[2][10];
  #pragma unroll
  for (int nt = 0; nt < 2; ++nt) {
    const unsigned short* wp =
        w_bf + ((size_t)((wave*2 + nt)*10)*4 + quad)*16*8 + (size_t)l15*8;
    #pragma unroll
    for (int kc = 0; kc < 10; ++kc)
      wf[nt][kc] = *(const bf16x8*)(wp + (size_t)kc*4*16*8);
  }

  f32x4 acc[8][2];
  #pragma unroll
  for (int mt = 0; mt < 8; ++mt) {
    acc[mt][0] = (f32x4){0.f, 0.f, 0.f, 0.f};
    acc[mt][1] = (f32x4){0.f, 0.f, 0.f, 0.f};
  }

  const int ar = tid >> 2;            // A row 0..127
  const int ac = (tid & 3) * 8;       // A col base 0/8/16/24
  const float* xrow = x + (size_t)(m0 + ar) * IN_DIM;

  F8 av[2];
  av[0] = load_x8(xrow, 0, ac);       // kc=0
  av[1] = load_x8(xrow, 32, ac);      // kc=1
  {
    u32x4 pk;
    pk.x = cvtpk(av[0].v[0], av[0].v[1]);
    pk.y = cvtpk(av[0].v[2], av[0].v[3]);
    pk.z = cvtpk(av[0].v[4], av[0].v[5]);
    pk.w = cvtpk(av[0].v[6], av[0].v[7]);
    *(u32x4*)&a_lds[0][ar][(tid & 3) * 4] = pk;
  }
  barrier_lgkm();

  #pragma unroll
  for (int kc = 0; kc < 10; ++kc) {
    const int cur = kc & 1;
    bf16x8 afr[8];
    #pragma unroll
    for (int mt = 0; mt < 8; ++mt)
      afr[mt] = *(const bf16x8*)&a_lds[cur][mt*16 + l15][quad*4];
    if (kc < 9) {
      const int s = (kc + 1) & 1;
      u32x4 pk;
      pk.x = cvtpk(av[s].v[0], av[s].v[1]);
      pk.y = cvtpk(av[s].v[2], av[s].v[3]);
      pk.z = cvtpk(av[s].v[4], av[s].v[5]);
      pk.w = cvtpk(av[s].v[6], av[s].v[7]);
      *(u32x4*)&a_lds[s][ar][(tid & 3) * 4] = pk;
    }
    if (kc < 8)
      av[kc & 1] = load_x8(xrow, (kc + 2) * 32, ac);
    #pragma unroll
    for (int mt = 0; mt < 8; ++mt) {
      acc[mt][0] = __builtin_amdgcn_mfma_f32_16x16x32_bf16(afr[mt], wf[0][kc], acc[mt][0], 0, 0, 0);
      acc[mt][1] = __builtin_amdgcn_mfma_f32_16x16x32_bf16(afr[mt], wf[1][kc], acc[mt][1], 0, 0, 0);
    }
    barrier_lgkm();
  }

  // epilogue: scatter to scan-permuted layout (bit-identical formula/rounding)
  const int t  = (int)(blockIdx.x >> 1);
  const int b4 = ((int)blockIdx.x & 1) * 32;
  #pragma unroll
  for (int nt = 0; nt < 2; ++nt) {
    const int n = wave*32 + nt*16 + l15;
    const float kb = 2.0f * (b_ih[n] + b_hh[n]);
    const int tid_lo = wave*64 + nt*16 + l15;
    #pragma unroll
    for (int mt = 0; mt < 8; ++mt) {
      const int g = b4 + mt*4 + quad;
      const size_t base = ((size_t)t*64 + g) * 512;
      float y0 = fmaf(2.0f, acc[mt][nt][0], kb);
      float y1 = fmaf(2.0f, acc[mt][nt][1], kb);
      float y2 = fmaf(2.0f, acc[mt][nt][2], kb);
      float y3 = fmaf(2.0f, acc[mt][nt][3], kb);
      xp2[base + tid_lo]      = cvtpk(y0, y1);
      xp2[base + tid_lo + 32] = cvtpk(y2, y3);
    }
  }
}

// ---------------- kernel 2: sequential scan. RESTRUCTURE: 64 blocks x 256
// thr (4 waves). Theory: the 8-wave version was LDS-read-throughput bound
// (8 waves x 8 ds_read_b128 = 64 KB/step through the CU's single LDS pipe
// ~= 770 of the 1054 cy/step; every wave redundantly read the whole
// h-matrix). 4 waves halve that. Wave w owns n-tiles {2w,2w+1,2w+8,2w+9}
// (cols [32w,32w+32) u [32w+128,32w+160)). Thread t reads xp2 dwords t and
// t+256: by the layout map these hold exactly (col_e, col_e+128) for
// batches (rb, rb+1) -- no xp2 layout change. Per-(batch,col) arithmetic
// (afr bytes, wf values, kc-parity A/B accumulate order, fmaf/exp/rcp,
// f2bf_fast) is bit-identical to the 224-us round-2 kernel.
__global__ __launch_bounds__(256, 1) void rnn_scan(const float* __restrict__ W_hh,
    const unsigned int* __restrict__ xp2, float* __restrict__ hT)
{
  __shared__ alignas(16) unsigned short hbuf[2][4 * 272];
  const int tid  = threadIdx.x;
  const int wave = tid >> 6;
  const int lane = tid & 63;
  const int l15  = lane & 15;
  const int quad = lane >> 4;
  const int g = blockIdx.x;

  // B fragments: 4 n-tiles per wave: n16 = 2w + (nt&1) + (nt>>1)*8
  // B[k=quad*8+j][n=n16*16+l15] = W_hh[n][k]
  bf16x8 wf[4][8];
  #pragma unroll
  for (int nt = 0; nt < 4; ++nt) {
    const int n16 = 2*wave + (nt & 1) + (nt >> 1) * 8;
    const int n = n16 * 16 + l15;
    #pragma unroll
    for (int kc = 0; kc < 8; ++kc) {
      const float* src = W_hh + n*HID + kc*32 + quad*8;
      float4 p0 = *(const float4*)src;
      float4 p1 = *(const float4*)(src + 4);
      wf[nt][kc] = cvt8(p0.x,p0.y,p0.z,p0.w,p1.x,p1.y,p1.z,p1.w);
    }
  }

  const int rb    = (quad >> 1) * 2;                  // batch pair: rb, rb+1
  const int col_e = 32*wave + (quad & 1) * 16 + l15;  // lo hidden col (hi = +128)
  const int abase = (l15 & 3) * 272 + quad * 8;       // A-frag read base

  for (int i = tid; i < 4 * 272; i += 256) hbuf[0][i] = 0;  // h0 = 0

  const unsigned int* xbase = xp2 + (size_t)g * 512 + tid;  // t stride 64*512 dwords

  __syncthreads();

  unsigned int xq[16], xqn[16];
  #pragma unroll
  for (int j = 0; j < 8; ++j) {                      // preload tc=0 (8 steps)
    xq[2*j]   = xbase[(size_t)j * 32768];
    xq[2*j+1] = xbase[(size_t)j * 32768 + 256];
  }

  for (int tc = 0; tc < SEQ / 8; ++tc) {
    if (tc < SEQ/8 - 1) {                            // issue tc+1 burst early
      const unsigned int* pn = xbase + (size_t)(tc + 1) * 8 * 32768;
      #pragma unroll
      for (int j = 0; j < 8; ++j) {
        xqn[2*j]   = pn[(size_t)j * 32768];
        xqn[2*j+1] = pn[(size_t)j * 32768 + 256];
      }
    }
    #pragma unroll
    for (int j = 0; j < 8; ++j) {
      const int cur = j & 1;                         // global step parity == j&1
      bf16x8 afr[8];
      #pragma unroll
      for (int kc = 0; kc < 8; ++kc)
        afr[kc] = *(const bf16x8*)&hbuf[cur][abase + kc*32];
      f32x4 z = (f32x4){0.f,0.f,0.f,0.f};
      f32x4 aA0 = z, aA1 = z, aA2 = z, aA3 = z;
      f32x4 aB0 = z, aB1 = z, aB2 = z, aB3 = z;
      #pragma unroll
      for (int kc = 0; kc < 8; kc += 2) {
        aA0 = __builtin_amdgcn_mfma_f32_16x16x32_bf16(afr[kc],   wf[0][kc],   aA0, 0, 0, 0);
        aA1 = __builtin_amdgcn_mfma_f32_16x16x32_bf16(afr[kc],   wf[1][kc],   aA1, 0, 0, 0);
        aA2 = __builtin_amdgcn_mfma_f32_16x16x32_bf16(afr[kc],   wf[2][kc],   aA2, 0, 0, 0);
        aA3 = __builtin_amdgcn_mfma_f32_16x16x32_bf16(afr[kc],   wf[3][kc],   aA3, 0, 0, 0);
        aB0 = __builtin_amdgcn_mfma_f32_16x16x32_bf16(afr[kc+1], wf[0][kc+1], aB0, 0, 0, 0);
        aB1 = __builtin_amdgcn_mfma_f32_16x16x32_bf16(afr[kc+1], wf[1][kc+1], aB1, 0, 0, 0);
        aB2 = __builtin_amdgcn_mfma_f32_16x16x32_bf16(afr[kc+1], wf[2][kc+1], aB2, 0, 0, 0);
        aB3 = __builtin_amdgcn_mfma_f32_16x16x32_bf16(afr[kc+1], wf[3][kc+1], aB3, 0, 0, 0);
      }
      f32x4 s0 = aA0 + aB0;   // tile 2w    (lo, quad&1==0)
      f32x4 s1 = aA1 + aB1;   // tile 2w+1  (lo, quad&1==1)
      f32x4 s2 = aA2 + aB2;   // tile 2w+8  (hi, quad&1==0)
      f32x4 s3 = aA3 + aB3;   // tile 2w+9  (hi, quad&1==1)
      f32x4 lo = (quad & 1) ? s1 : s0;
      f32x4 hi = (quad & 1) ? s3 : s2;
      // D reg i = batch i (row = quad*4+i, batch = row&3 = i)
      float v00 = (quad >> 1) ? lo[2] : lo[0];   // batch rb,   col_e
      float v10 = (quad >> 1) ? lo[3] : lo[1];   // batch rb+1, col_e
      float v01 = (quad >> 1) ? hi[2] : hi[0];   // batch rb,   col_e+128
      float v11 = (quad >> 1) ? hi[3] : hi[1];   // batch rb+1, col_e+128
      const unsigned int xlo = xq[2*j], xhi = xq[2*j+1];
      float y00 = fmaf(2.0f, v00, bitsf(xlo << 16));
      float y10 = fmaf(2.0f, v10, bitsf(xlo & 0xffff0000u));
      float y01 = fmaf(2.0f, v01, bitsf(xhi << 16));
      float y11 = fmaf(2.0f, v11, bitsf(xhi & 0xffff0000u));
      float h00 = fmaf(-2.0f, __builtin_amdgcn_rcpf(__expf(y00) + 1.0f), 1.0f);
      float h10 = fmaf(-2.0f, __builtin_amdgcn_rcpf(__expf(y10) + 1.0f), 1.0f);
      float h01 = fmaf(-2.0f, __builtin_amdgcn_rcpf(__expf(y01) + 1.0f), 1.0f);
      float h11 = fmaf(-2.0f, __builtin_amdgcn_rcpf(__expf(y11) + 1.0f), 1.0f);
      if (j < 7 || tc < SEQ/8 - 1) {
        hbuf[1 - cur][ rb      * 272 + col_e      ] = f2bf_fast(h00);
        hbuf[1 - cur][(rb + 1) * 272 + col_e      ] = f2bf_fast(h10);
        hbuf[1 - cur][ rb      * 272 + col_e + 128] = f2bf_fast(h01);
        hbuf[1 - cur][(rb + 1) * 272 + col_e + 128] = f2bf_fast(h11);
      } else {
        hT[(size_t)(g*4 + rb    ) * HID + col_e      ] = h00;
        hT[(size_t)(g*4 + rb + 1) * HID + col_e      ] = h10;
        hT[(size_t)(g*4 + rb    ) * HID + col_e + 128] = h01;
        hT[(size_t)(g*4 + rb + 1) * HID + col_e + 128] = h11;
      }
      barrier_lgkm();                                // no vmcnt(0) drain
    }
    if (tc < SEQ/8 - 1) {
      #pragma unroll
      for (int j = 0; j < 16; ++j)                   // rotate: loads had a
        xq[j] = xqn[j];                              // full tc to land
    }
  }
}

// ---------------- kernel 3: logits + log_softmax. 1 wave/batch.
__global__ __launch_bounds__(64) void fc_head(const float* __restrict__ hT,
    const float* __restrict__ W_fc, const float* __restrict__ b_fc,
    float* __restrict__ out)
{
  const int b = blockIdx.x;
  const int l = threadIdx.x;
  float s0 = 0.f, s1 = 0.f;
  #pragma unroll
  for (int j0 = 0; j0 < HID; j0 += 64) {
    float h = hT[(size_t)b * HID + j0 + l];
    s0 += h * W_fc[j0 + l];
    s1 += h * W_fc[HID + j0 + l];
  }
  #pragma unroll
  for (int off = 32; off > 0; off >>= 1) {
    s0 += __shfl_xor(s0, off, 64);
    s1 += __shfl_xor(s1, off, 64);
  }
  if (l == 0) {
    float l0 = s0 + b_fc[0], l1 = s1 + b_fc[1];
    float m = fmaxf(l0, l1);
    float lse = m + logf(expf(l0 - m) + expf(l1 - m));
    out[b*2 + 0] = l0 - lse;
    out[b*2 + 1] = l1 - lse;
  }
}

extern "C" void kernel_launch(void* const* d_in, const int* in_sizes, int n_in,
                              void* d_out, int out_size, void* d_ws, size_t ws_size,
                              hipStream_t stream) {
  const float* x    = (const float*)d_in[0];
  const float* W_ih = (const float*)d_in[1];
  const float* W_hh = (const float*)d_in[2];
  const float* b_ih = (const float*)d_in[3];
  const float* b_hh = (const float*)d_in[4];
  const float* W_fc = (const float*)d_in[5];
  const float* b_fc = (const float*)d_in[6];
  float* out = (float*)d_out;

  const size_t xp_bytes = (size_t)SEQ * BATCH * HID * 2;   // 67,108,864
  const size_t wb_bytes = (size_t)256 * 320 * 2;
  const size_t ht_bytes = (size_t)BATCH * HID * 4;
  if (ws_size < xp_bytes + wb_bytes + ht_bytes) return;

  char* ws = (char*)d_ws;
  unsigned int*   xp2  = (unsigned int*)ws;
  unsigned short* w_bf = (unsigned short*)(ws + xp_bytes);
  float*          hT   = (float*)(ws + xp_bytes + wb_bytes);

  hipLaunchKernelGGL(conv_wih, dim3(320),  dim3(256), 0, stream, W_ih, w_bf);
  hipLaunchKernelGGL(gemm_xp,  dim3(1024), dim3(512), 0, stream, x, w_bf, b_ih, b_hh, xp2);
  hipLaunchKernelGGL(rnn_scan, dim3(64),   dim3(256), 0, stream, W_hh, xp2, hT);
  hipLaunchKernelGGL(fc_head,  dim3(BATCH), dim3(64), 0, stream, hT, W_fc, b_fc, out);
}

// Round 6
// 552.690 us; speedup vs baseline: 1.0160x; 1.0160x over previous
//
#include <hip/hip_runtime.h>
#include <hip/hip_bf16.h>
#include <cstdint>
#include <cstddef>

#define SEQ 512
#define BATCH 256
#define IN_DIM 300
#define HID 256

typedef __attribute__((ext_vector_type(8))) short bf16x8;
typedef __attribute__((ext_vector_type(4))) float f32x4;
typedef __attribute__((ext_vector_type(4))) unsigned int u32x4;

__device__ __forceinline__ unsigned short f2bf(float f) {
  union { float f; unsigned int u; } v; v.f = f;
  unsigned int u = v.u;
  return (unsigned short)((u + 0x7fffu + ((u >> 16) & 1u)) >> 16);  // RNE
}
__device__ __forceinline__ unsigned short f2bf_fast(float f) {
  union { float f; unsigned int u; } v; v.f = f;
  return (unsigned short)((v.u + 0x8000u) >> 16);  // round-half-up, err <= 2^-9 rel
}
__device__ __forceinline__ float bitsf(unsigned int u) {
  union { unsigned int u; float f; } v; v.u = u; return v.f;
}
// HW cvt_pk RNE pack of two f32 -> one dword (low = lo).
__device__ __forceinline__ unsigned int cvtpk(float lo, float hi) {
  union { __hip_bfloat162 h; unsigned int u; } c;
  c.h = __float22bfloat162_rn(make_float2(lo, hi));
  return c.u;
}
__device__ __forceinline__ bf16x8 cvt8(float a0,float a1,float a2,float a3,
                                       float a4,float a5,float a6,float a7) {
  union { __hip_bfloat162 h2[4]; bf16x8 v; } c;
  c.h2[0] = __float22bfloat162_rn(make_float2(a0, a1));
  c.h2[1] = __float22bfloat162_rn(make_float2(a2, a3));
  c.h2[2] = __float22bfloat162_rn(make_float2(a4, a5));
  c.h2[3] = __float22bfloat162_rn(make_float2(a6, a7));
  return c.v;
}
// Raw workgroup barrier with LDS-only drain (keeps global prefetches in flight).
__device__ __forceinline__ void barrier_lgkm() {
  asm volatile("s_waitcnt lgkmcnt(0)" ::: "memory");
  __builtin_amdgcn_s_barrier();
  asm volatile("" ::: "memory");
}
// Raw barrier (no waitcnt) with compiler reorder fences.
__device__ __forceinline__ void barrier_raw() {
  asm volatile("" ::: "memory");
  __builtin_amdgcn_s_barrier();
  asm volatile("" ::: "memory");
}

struct F8 { float v[8]; };
__device__ __forceinline__ F8 load_x8(const float* __restrict__ xrow, int k0, int ac) {
  F8 r;
  if (k0 + ac + 8 <= IN_DIM) {
    float2 p0 = *(const float2*)(xrow + k0 + ac + 0);
    float2 p1 = *(const float2*)(xrow + k0 + ac + 2);
    float2 p2 = *(const float2*)(xrow + k0 + ac + 4);
    float2 p3 = *(const float2*)(xrow + k0 + ac + 6);
    r.v[0]=p0.x; r.v[1]=p0.y; r.v[2]=p1.x; r.v[3]=p1.y;
    r.v[4]=p2.x; r.v[5]=p2.y; r.v[6]=p3.x; r.v[7]=p3.y;
  } else {
    #pragma unroll
    for (int j = 0; j < 8; ++j)
      r.v[j] = (k0 + ac + j < IN_DIM) ? xrow[k0 + ac + j] : 0.f;
  }
  return r;
}

// ---------------- kernel 0: W_ih fp32 -> bf16 fragment-major; also zeroes done[]
__global__ __launch_bounds__(256) void conv_wih(const float* __restrict__ w,
                                                unsigned short* __restrict__ w_bf,
                                                unsigned int* __restrict__ done) {
  int idx = blockIdx.x * 256 + threadIdx.x;    // 0..81919
  if (idx < SEQ) done[idx] = 0;                // reset flags every graph replay
  int j    = idx & 7;
  int l15  = (idx >> 3) & 15;
  int quad = (idx >> 7) & 3;
  int t    = idx >> 9;                         // n16*10 + kc
  int n16  = t / 10;
  int kc   = t - n16 * 10;
  int n = n16 * 16 + l15;
  int k = kc * 32 + quad * 8 + j;
  float v = (k < IN_DIM) ? w[n * IN_DIM + k] : 0.f;
  w_bf[idx] = f2bf(v);
}

// Consumer-side: wait until window w (t = 16w..16w+15) fully produced (done==2).
__device__ __forceinline__ void wait_window(const unsigned int* __restrict__ done, int w) {
  if (w < SEQ / 16) {
    if (threadIdx.x == 0) {
      const int t0 = w * 16;
      #pragma unroll 1
      for (int i = 0; i < 16; ++i)
        while (__hip_atomic_load(&done[t0 + i], __ATOMIC_RELAXED,
                                 __HIP_MEMORY_SCOPE_AGENT) < 2u)
          __builtin_amdgcn_s_sleep(8);
      __threadfence();                         // acquire: invalidate stale L1/L2
    }
    barrier_raw();                             // release all waves past the wait
  }
}

// ---------------- fused kernel: blocks 0..63 = scan consumers (exact round-2/4
// 8-wave code), blocks 64..1087 = xp2 producers (exact round-3/4 gemm code).
// Producers publish done[t] += 1 (2 blocks per t) after a vmcnt-draining
// __syncthreads + device fence; consumers spin (relaxed) + fence + barrier,
// pipelined two 16-step windows ahead of consumption. Producers never wait ->
// no deadlock (64 consumer blocks cannot occupy all 256 CUs).
__global__ __launch_bounds__(512, 2) void rnn_fused(const float* __restrict__ x,
    const unsigned short* __restrict__ w_bf, const float* __restrict__ b_ih,
    const float* __restrict__ b_hh, const float* __restrict__ W_hh,
    unsigned int* __restrict__ xp2, float* __restrict__ hT,
    unsigned int* __restrict__ done)
{
  __shared__ alignas(16) unsigned char lds_raw[20480];
  const int tid  = threadIdx.x;
  const int wave = tid >> 6;
  const int lane = tid & 63;
  const int l15  = lane & 15;
  const int quad = lane >> 4;

  if (blockIdx.x >= 64) {
    // ================= PRODUCER: xp2 = 2*(x@W_ih^T + b_ih + b_hh) =================
    typedef unsigned int ALds[128][20];
    ALds* a_lds = (ALds*)lds_raw;              // [2][128][20] dwords, row 80 B
    const int bx = (int)blockIdx.x - 64;
    const long m0 = (long)bx * 128;

    bf16x8 wf[2][10];
    #pragma unroll
    for (int nt = 0; nt < 2; ++nt) {
      const unsigned short* wp =
          w_bf + ((size_t)((wave*2 + nt)*10)*4 + quad)*16*8 + (size_t)l15*8;
      #pragma unroll
      for (int kc = 0; kc < 10; ++kc)
        wf[nt][kc] = *(const bf16x8*)(wp + (size_t)kc*4*16*8);
    }

    f32x4 acc[8][2];
    #pragma unroll
    for (int mt = 0; mt < 8; ++mt) {
      acc[mt][0] = (f32x4){0.f, 0.f, 0.f, 0.f};
      acc[mt][1] = (f32x4){0.f, 0.f, 0.f, 0.f};
    }

    const int ar = tid >> 2;
    const int ac = (tid & 3) * 8;
    const float* xrow = x + (size_t)(m0 + ar) * IN_DIM;

    F8 av[2];
    av[0] = load_x8(xrow, 0, ac);
    av[1] = load_x8(xrow, 32, ac);
    {
      u32x4 pk;
      pk.x = cvtpk(av[0].v[0], av[0].v[1]);
      pk.y = cvtpk(av[0].v[2], av[0].v[3]);
      pk.z = cvtpk(av[0].v[4], av[0].v[5]);
      pk.w = cvtpk(av[0].v[6], av[0].v[7]);
      *(u32x4*)&a_lds[0][ar][(tid & 3) * 4] = pk;
    }
    barrier_lgkm();

    #pragma unroll
    for (int kc = 0; kc < 10; ++kc) {
      const int cur = kc & 1;
      bf16x8 afr[8];
      #pragma unroll
      for (int mt = 0; mt < 8; ++mt)
        afr[mt] = *(const bf16x8*)&a_lds[cur][mt*16 + l15][quad*4];
      if (kc < 9) {
        const int s = (kc + 1) & 1;
        u32x4 pk;
        pk.x = cvtpk(av[s].v[0], av[s].v[1]);
        pk.y = cvtpk(av[s].v[2], av[s].v[3]);
        pk.z = cvtpk(av[s].v[4], av[s].v[5]);
        pk.w = cvtpk(av[s].v[6], av[s].v[7]);
        *(u32x4*)&a_lds[s][ar][(tid & 3) * 4] = pk;
      }
      if (kc < 8)
        av[kc & 1] = load_x8(xrow, (kc + 2) * 32, ac);
      #pragma unroll
      for (int mt = 0; mt < 8; ++mt) {
        acc[mt][0] = __builtin_amdgcn_mfma_f32_16x16x32_bf16(afr[mt], wf[0][kc], acc[mt][0], 0, 0, 0);
        acc[mt][1] = __builtin_amdgcn_mfma_f32_16x16x32_bf16(afr[mt], wf[1][kc], acc[mt][1], 0, 0, 0);
      }
      barrier_lgkm();
    }

    const int t  = bx >> 1;
    const int b4 = (bx & 1) * 32;
    #pragma unroll
    for (int nt = 0; nt < 2; ++nt) {
      const int n = wave*32 + nt*16 + l15;
      const float kb = 2.0f * (b_ih[n] + b_hh[n]);
      const int tid_lo = wave*64 + nt*16 + l15;
      #pragma unroll
      for (int mt = 0; mt < 8; ++mt) {
        const int g = b4 + mt*4 + quad;
        const size_t base = ((size_t)t*64 + g) * 512;
        float y0 = fmaf(2.0f, acc[mt][nt][0], kb);
        float y1 = fmaf(2.0f, acc[mt][nt][1], kb);
        float y2 = fmaf(2.0f, acc[mt][nt][2], kb);
        float y3 = fmaf(2.0f, acc[mt][nt][3], kb);
        xp2[base + tid_lo]      = cvtpk(y0, y1);
        xp2[base + tid_lo + 32] = cvtpk(y2, y3);
      }
    }
    // publish: __syncthreads drains vmcnt(0) for all threads' stores, then
    // device fence (L2 writeback) + relaxed RMW = release.
    __syncthreads();
    if (tid == 0) {
      __threadfence();
      __hip_atomic_fetch_add(&done[t], 1u, __ATOMIC_RELAXED, __HIP_MEMORY_SCOPE_AGENT);
    }
    return;
  }

  // ================= CONSUMER: sequential scan (exact round-2/4 code) =================
  typedef unsigned short HBuf[4 * 272];
  HBuf* hbuf = (HBuf*)lds_raw;                 // [2][1088] shorts
  const int g = blockIdx.x;
  const int c0 = wave * 32;

  bf16x8 wf[2][8];
  #pragma unroll
  for (int nt = 0; nt < 2; ++nt) {
    const int n = c0 + nt*16 + l15;
    #pragma unroll
    for (int kc = 0; kc < 8; ++kc) {
      const float* src = W_hh + n*HID + kc*32 + quad*8;
      float4 p0 = *(const float4*)src;
      float4 p1 = *(const float4*)(src + 4);
      wf[nt][kc] = cvt8(p0.x,p0.y,p0.z,p0.w,p1.x,p1.y,p1.z,p1.w);
    }
  }

  const int rb    = (quad >> 1) * 2;
  const int col_e = c0 + (quad & 1) * 16 + l15;
  const int abase = (l15 & 3) * 272 + quad * 8;

  for (int i = tid; i < 4 * 272; i += 512) hbuf[0][i] = 0;

  const unsigned int* xbase = xp2 + (size_t)g * 512 + tid;

  __syncthreads();

  unsigned int xq[16], xqn[16];
  wait_window(done, 0);
  #pragma unroll
  for (int j = 0; j < 16; ++j)
    xq[j] = xbase[(size_t)j * 32768];
  wait_window(done, 1);

  for (int tc = 0; tc < SEQ / 16; ++tc) {
    wait_window(done, tc + 2);                 // pipelined 2 windows ahead
    if (tc < SEQ/16 - 1) {
      const unsigned int* pn = xbase + (size_t)(tc + 1) * 16 * 32768;
      #pragma unroll
      for (int j = 0; j < 16; ++j)
        xqn[j] = pn[(size_t)j * 32768];
    }
    #pragma unroll
    for (int j = 0; j < 16; ++j) {
      const int cur = j & 1;
      bf16x8 afr[8];
      #pragma unroll
      for (int kc = 0; kc < 8; ++kc)
        afr[kc] = *(const bf16x8*)&hbuf[cur][abase + kc*32];
      f32x4 a0A = (f32x4){0.f,0.f,0.f,0.f}, a0B = a0A, a1A = a0A, a1B = a0A;
      #pragma unroll
      for (int kc = 0; kc < 8; kc += 2) {
        a0A = __builtin_amdgcn_mfma_f32_16x16x32_bf16(afr[kc],   wf[0][kc],   a0A, 0, 0, 0);
        a1A = __builtin_amdgcn_mfma_f32_16x16x32_bf16(afr[kc],   wf[1][kc],   a1A, 0, 0, 0);
        a0B = __builtin_amdgcn_mfma_f32_16x16x32_bf16(afr[kc+1], wf[0][kc+1], a0B, 0, 0, 0);
        a1B = __builtin_amdgcn_mfma_f32_16x16x32_bf16(afr[kc+1], wf[1][kc+1], a1B, 0, 0, 0);
      }
      f32x4 acc0 = a0A + a0B;
      f32x4 acc1 = a1A + a1B;
      f32x4 a = (quad & 1) ? acc1 : acc0;
      float s0 = (quad >> 1) ? a[2] : a[0];
      float s1 = (quad >> 1) ? a[3] : a[1];
      float xv0 = bitsf(xq[j] << 16);
      float xv1 = bitsf(xq[j] & 0xffff0000u);
      float y0 = fmaf(2.0f, s0, xv0);
      float y1 = fmaf(2.0f, s1, xv1);
      float h0 = fmaf(-2.0f, __builtin_amdgcn_rcpf(__expf(y0) + 1.0f), 1.0f);
      float h1 = fmaf(-2.0f, __builtin_amdgcn_rcpf(__expf(y1) + 1.0f), 1.0f);
      if (j < 15 || tc < SEQ/16 - 1) {
        hbuf[1 - cur][ rb      * 272 + col_e] = f2bf_fast(h0);
        hbuf[1 - cur][(rb + 1) * 272 + col_e] = f2bf_fast(h1);
      } else {
        hT[(size_t)(g*4 + rb    ) * HID + col_e] = h0;
        hT[(size_t)(g*4 + rb + 1) * HID + col_e] = h1;
      }
      barrier_lgkm();
    }
    if (tc < SEQ/16 - 1) {
      #pragma unroll
      for (int j = 0; j < 16; ++j)
        xq[j] = xqn[j];
    }
  }
}

// ---------------- kernel 3: logits + log_softmax. 1 wave/batch.
__global__ __launch_bounds__(64) void fc_head(const float* __restrict__ hT,
    const float* __restrict__ W_fc, const float* __restrict__ b_fc,
    float* __restrict__ out)
{
  const int b = blockIdx.x;
  const int l = threadIdx.x;
  float s0 = 0.f, s1 = 0.f;
  #pragma unroll
  for (int j0 = 0; j0 < HID; j0 += 64) {
    float h = hT[(size_t)b * HID + j0 + l];
    s0 += h * W_fc[j0 + l];
    s1 += h * W_fc[HID + j0 + l];
  }
  #pragma unroll
  for (int off = 32; off > 0; off >>= 1) {
    s0 += __shfl_xor(s0, off, 64);
    s1 += __shfl_xor(s1, off, 64);
  }
  if (l == 0) {
    float l0 = s0 + b_fc[0], l1 = s1 + b_fc[1];
    float m = fmaxf(l0, l1);
    float lse = m + logf(expf(l0 - m) + expf(l1 - m));
    out[b*2 + 0] = l0 - lse;
    out[b*2 + 1] = l1 - lse;
  }
}

extern "C" void kernel_launch(void* const* d_in, const int* in_sizes, int n_in,
                              void* d_out, int out_size, void* d_ws, size_t ws_size,
                              hipStream_t stream) {
  const float* x    = (const float*)d_in[0];
  const float* W_ih = (const float*)d_in[1];
  const float* W_hh = (const float*)d_in[2];
  const float* b_ih = (const float*)d_in[3];
  const float* b_hh = (const float*)d_in[4];
  const float* W_fc = (const float*)d_in[5];
  const float* b_fc = (const float*)d_in[6];
  float* out = (float*)d_out;

  const size_t xp_bytes = (size_t)SEQ * BATCH * HID * 2;   // 67,108,864
  const size_t wb_bytes = (size_t)256 * 320 * 2;
  const size_t ht_bytes = (size_t)BATCH * HID * 4;
  const size_t dn_bytes = (size_t)SEQ * 4;                 // done flags
  if (ws_size < xp_bytes + wb_bytes + ht_bytes + dn_bytes) return;

  char* ws = (char*)d_ws;
  unsigned int*   xp2  = (unsigned int*)ws;
  unsigned short* w_bf = (unsigned short*)(ws + xp_bytes);
  float*          hT   = (float*)(ws + xp_bytes + wb_bytes);
  unsigned int*   done = (unsigned int*)(ws + xp_bytes + wb_bytes + ht_bytes);

  hipLaunchKernelGGL(conv_wih,  dim3(320),   dim3(256), 0, stream, W_ih, w_bf, done);
  hipLaunchKernelGGL(rnn_fused, dim3(1088),  dim3(512), 0, stream,
                     x, w_bf, b_ih, b_hh, W_hh, xp2, hT, done);
  hipLaunchKernelGGL(fc_head,   dim3(BATCH), dim3(64),  0, stream, hT, W_fc, b_fc, out);
}

// Round 8
// 530.082 us; speedup vs baseline: 1.0593x; 1.0427x over previous
//
#include <hip/hip_runtime.h>
#include <hip/hip_bf16.h>
#include <cstdint>
#include <cstddef>

#define SEQ 512
#define BATCH 256
#define IN_DIM 300
#define HID 256

typedef __attribute__((ext_vector_type(8))) short bf16x8;
typedef __attribute__((ext_vector_type(4))) float f32x4;

__device__ __forceinline__ unsigned short f2bf(float f) {
  union { float f; unsigned int u; } v; v.f = f;
  unsigned int u = v.u;
  return (unsigned short)((u + 0x7fffu + ((u >> 16) & 1u)) >> 16);  // RNE
}
__device__ __forceinline__ unsigned short f2bf_fast(float f) {
  union { float f; unsigned int u; } v; v.f = f;
  return (unsigned short)((v.u + 0x8000u) >> 16);  // round-half-up
}
__device__ __forceinline__ float bitsf(unsigned int u) {
  union { unsigned int u; float f; } v; v.u = u; return v.f;
}
__device__ __forceinline__ unsigned int cvtpk(float lo, float hi) {
  union { __hip_bfloat162 h; unsigned int u; } c;
  c.h = __float22bfloat162_rn(make_float2(lo, hi));
  return c.u;
}
__device__ __forceinline__ bf16x8 cvt8(float a0,float a1,float a2,float a3,
                                       float a4,float a5,float a6,float a7) {
  union { __hip_bfloat162 h2[4]; bf16x8 v; } c;
  c.h2[0] = __float22bfloat162_rn(make_float2(a0, a1));
  c.h2[1] = __float22bfloat162_rn(make_float2(a2, a3));
  c.h2[2] = __float22bfloat162_rn(make_float2(a4, a5));
  c.h2[3] = __float22bfloat162_rn(make_float2(a6, a7));
  return c.v;
}
// LDS-drain-only workgroup barrier (global prefetches stay in flight).
__device__ __forceinline__ void barrier_lgkm() {
  asm volatile("s_waitcnt lgkmcnt(0)" ::: "memory");
  __builtin_amdgcn_s_barrier();
  asm volatile("" ::: "memory");
}

// ---------------- kernel 0: W_ih fp32 -> bf16, FRAGMENT-MAJOR (round-4).
// Short index: (((n16*10 + kc)*4 + quad)*16 + l15)*8 + j
//   value = W_ih[n16*16 + l15][kc*32 + quad*8 + j]  (0 if k >= 300)
__global__ __launch_bounds__(256) void conv_wih(const float* __restrict__ w,
                                                unsigned short* __restrict__ w_bf) {
  int idx = blockIdx.x * 256 + threadIdx.x;    // 0..81919
  int j    = idx & 7;
  int l15  = (idx >> 3) & 15;
  int quad = (idx >> 7) & 3;
  int t    = idx >> 9;
  int n16  = t / 10;
  int kc   = t - n16 * 10;
  int n = n16 * 16 + l15;
  int k = kc * 32 + quad * 8 + j;
  float v = (k < IN_DIM) ? w[n * IN_DIM + k] : 0.f;
  w_bf[idx] = f2bf(v);
}

// Window-GEMM: xpbuf = 2*(x_window @ W_ih^T + b) in the scan's dword layout.
// acc order over kc identical to the verified gemm_xp -> bit-identical values.
__device__ __forceinline__ void win_gemm(const unsigned int* __restrict__ a_lds,
    unsigned int* __restrict__ xpbuf, const bf16x8 wfi[2][10],
    float kb0, float kb1, int wave, int l15, int quad)
{
  f32x4 acc[2][2];
  #pragma unroll
  for (int mt = 0; mt < 2; ++mt) {
    acc[mt][0] = (f32x4){0.f,0.f,0.f,0.f};
    acc[mt][1] = (f32x4){0.f,0.f,0.f,0.f};
  }
  #pragma unroll
  for (int kc = 0; kc < 10; ++kc) {
    bf16x8 afr0 = *(const bf16x8*)&a_lds[(     l15) * 164 + kc*16 + quad*4];
    bf16x8 afr1 = *(const bf16x8*)&a_lds[(16 + l15) * 164 + kc*16 + quad*4];
    acc[0][0] = __builtin_amdgcn_mfma_f32_16x16x32_bf16(afr0, wfi[0][kc], acc[0][0], 0, 0, 0);
    acc[0][1] = __builtin_amdgcn_mfma_f32_16x16x32_bf16(afr0, wfi[1][kc], acc[0][1], 0, 0, 0);
    acc[1][0] = __builtin_amdgcn_mfma_f32_16x16x32_bf16(afr1, wfi[0][kc], acc[1][0], 0, 0, 0);
    acc[1][1] = __builtin_amdgcn_mfma_f32_16x16x32_bf16(afr1, wfi[1][kc], acc[1][1], 0, 0, 0);
  }
  #pragma unroll
  for (int nt = 0; nt < 2; ++nt) {
    const float kb = nt ? kb1 : kb0;
    const int tid_s = wave*64 + nt*16 + l15;
    #pragma unroll
    for (int mt = 0; mt < 2; ++mt) {
      const int idx = (mt*4 + quad) * 512 + tid_s;   // t_loc = mt*4+quad
      float y0 = fmaf(2.0f, acc[mt][nt][0], kb);
      float y1 = fmaf(2.0f, acc[mt][nt][1], kb);
      float y2 = fmaf(2.0f, acc[mt][nt][2], kb);
      float y3 = fmaf(2.0f, acc[mt][nt][3], kb);
      xpbuf[idx]      = cvtpk(y0, y1);
      xpbuf[idx + 32] = cvtpk(y2, y3);
    }
  }
}

__device__ __forceinline__ void win_stage(unsigned int* __restrict__ a_lds,
    const float4* __restrict__ xr, const int* __restrict__ sidx, int tid)
{
  #pragma unroll
  for (int i = 0; i < 5; ++i)
    if (i < 4 || tid < 352) {
      uint2 pk2;
      pk2.x = cvtpk(xr[i].x, xr[i].y);
      pk2.y = cvtpk(xr[i].z, xr[i].w);
      *(uint2*)&a_lds[sidx[i]] = pk2;
    }
}

// ---------------- THE kernel: per-block fused xp-GEMM + scan + FC head.
// 64 blocks x 512 thr. Window = 8 timesteps. Per window: x slice staged to
// LDS (loads issued during previous window's scan -> latency hidden),
// 40-MFMA/wave window-GEMM into LDS xpbuf (exact old xp2 dword layout),
// then 8 scan steps read xq from LDS. xp2 NEVER touches HBM. FC folded in.
__global__ __launch_bounds__(512, 2) void rnn_all(const float* __restrict__ x,
    const unsigned short* __restrict__ w_bf, const float* __restrict__ b_ih,
    const float* __restrict__ b_hh, const float* __restrict__ W_hh,
    const float* __restrict__ W_fc, const float* __restrict__ b_fc,
    float* __restrict__ out)
{
  __shared__ alignas(16) unsigned int   xpbuf[8 * 512];      // 16 KB
  __shared__ alignas(16) unsigned int   a_lds[32 * 164];     // 21 KB (rows: 320 bf16 + pad)
  __shared__ alignas(16) unsigned short hbuf[2][1088];       // 4.3 KB

  const int tid  = threadIdx.x;
  const int wave = tid >> 6;
  const int lane = tid & 63;
  const int l15  = lane & 15;
  const int quad = lane >> 4;
  const int g    = blockIdx.x;
  const int c0   = wave * 32;

  // W_hh fragments (scan B), exact round-2 path
  bf16x8 wfh[2][8];
  #pragma unroll
  for (int nt = 0; nt < 2; ++nt) {
    const int n = c0 + nt*16 + l15;
    #pragma unroll
    for (int kc = 0; kc < 8; ++kc) {
      const float* src = W_hh + n*HID + kc*32 + quad*8;
      float4 p0 = *(const float4*)src;
      float4 p1 = *(const float4*)(src + 4);
      wfh[nt][kc] = cvt8(p0.x,p0.y,p0.z,p0.w,p1.x,p1.y,p1.z,p1.w);
    }
  }
  // W_ih fragments (xp B), fragment-major coalesced (round-4 path), held in regs
  bf16x8 wfi[2][10];
  #pragma unroll
  for (int nt = 0; nt < 2; ++nt) {
    const unsigned short* wp =
        w_bf + ((size_t)((wave*2 + nt)*10)*4 + quad)*128 + (size_t)l15*8;
    #pragma unroll
    for (int kc = 0; kc < 10; ++kc)
      wfi[nt][kc] = *(const bf16x8*)(wp + (size_t)kc*512);
  }
  const float kb0 = 2.0f * (b_ih[c0 + l15]      + b_hh[c0 + l15]);
  const float kb1 = 2.0f * (b_ih[c0 + 16 + l15] + b_hh[c0 + 16 + l15]);

  // per-thread x-load offsets: 5 float4 over 32 rows x 75 slots (2400 total)
  unsigned int voff[5]; int sidx[5];
  #pragma unroll
  for (int i = 0; i < 5; ++i) {
    const int e = tid + i * 512;
    const int row = e / 75;
    const int c4  = e - row * 75;
    const int t_loc = row >> 2, b_loc = row & 3;
    voff[i] = (unsigned)(((t_loc * 256 + 4 * g + b_loc) * 300 + c4 * 4) * 4);
    sidx[i] = row * 164 + c4 * 2;
  }

  const int rb    = (quad >> 1) * 2;
  const int col_e = c0 + (quad & 1) * 16 + l15;
  const int abase = (l15 & 3) * 272 + quad * 8;

  for (int i = tid; i < 1088; i += 512) hbuf[0][i] = 0;          // h0 = 0
  if (tid < 320) a_lds[(tid / 10) * 164 + 150 + (tid % 10)] = 0; // zero k=300..319

  // issue + stage window 0, GEMM(0)
  float4 xr[5];
  #pragma unroll
  for (int i = 0; i < 5; ++i)
    if (i < 4 || tid < 352)
      xr[i] = *(const float4*)((const char*)x + voff[i]);
  __syncthreads();
  win_stage(a_lds, xr, sidx, tid);
  barrier_lgkm();
  win_gemm(a_lds, xpbuf, wfi, kb0, kb1, wave, l15, quad);
  barrier_lgkm();

  const size_t WSTRIDE = (size_t)8 * 256 * 300 * 4;   // bytes per window of x

  for (int w = 0; w < 64; ++w) {
    const char* pn = (const char*)x + (size_t)(w + 1) * WSTRIDE;
    #pragma unroll
    for (int j = 0; j < 8; ++j) {
      if (j == 0 && w < 63) {                  // issue next window's x loads
        #pragma unroll
        for (int i = 0; i < 5; ++i)
          if (i < 4 || tid < 352)
            xr[i] = *(const float4*)(pn + voff[i]);
      }
      const int cur = j & 1;                   // global parity = j&1 (8 even)
      const unsigned int xqj = xpbuf[j * 512 + tid];
      bf16x8 afr[8];
      #pragma unroll
      for (int kc = 0; kc < 8; ++kc)
        afr[kc] = *(const bf16x8*)&hbuf[cur][abase + kc*32];
      f32x4 a0A = (f32x4){0.f,0.f,0.f,0.f}, a0B = a0A, a1A = a0A, a1B = a0A;
      #pragma unroll
      for (int kc = 0; kc < 8; kc += 2) {
        a0A = __builtin_amdgcn_mfma_f32_16x16x32_bf16(afr[kc],   wfh[0][kc],   a0A, 0, 0, 0);
        a1A = __builtin_amdgcn_mfma_f32_16x16x32_bf16(afr[kc],   wfh[1][kc],   a1A, 0, 0, 0);
        a0B = __builtin_amdgcn_mfma_f32_16x16x32_bf16(afr[kc+1], wfh[0][kc+1], a0B, 0, 0, 0);
        a1B = __builtin_amdgcn_mfma_f32_16x16x32_bf16(afr[kc+1], wfh[1][kc+1], a1B, 0, 0, 0);
      }
      if (j == 5 && w < 63)                    // stage next window (a_lds free)
        win_stage(a_lds, xr, sidx, tid);
      f32x4 acc0 = a0A + a0B;
      f32x4 acc1 = a1A + a1B;
      f32x4 a = (quad & 1) ? acc1 : acc0;
      float s0 = (quad >> 1) ? a[2] : a[0];
      float s1 = (quad >> 1) ? a[3] : a[1];
      float xv0 = bitsf(xqj << 16);
      float xv1 = bitsf(xqj & 0xffff0000u);
      float y0 = fmaf(2.0f, s0, xv0);
      float y1 = fmaf(2.0f, s1, xv1);
      float h0 = fmaf(-2.0f, __builtin_amdgcn_rcpf(__expf(y0) + 1.0f), 1.0f);
      float h1 = fmaf(-2.0f, __builtin_amdgcn_rcpf(__expf(y1) + 1.0f), 1.0f);
      if (w == 63 && j == 7) {                 // final h -> f32 LDS for FC
        float* fcb = (float*)xpbuf;            // aliases rows consumed at j=0,1
        fcb[ rb      * 256 + col_e] = h0;
        fcb[(rb + 1) * 256 + col_e] = h1;
      } else {
        hbuf[1 - cur][ rb      * 272 + col_e] = f2bf_fast(h0);
        hbuf[1 - cur][(rb + 1) * 272 + col_e] = f2bf_fast(h1);
      }
      barrier_lgkm();
    }
    if (w < 63) {                              // produce next window's xpbuf
      win_gemm(a_lds, xpbuf, wfi, kb0, kb1, wave, l15, quad);
      barrier_lgkm();
    }
  }

  // FC head: wave b_loc handles batch 4g+b_loc (same math as old fc_head)
  if (wave < 4) {
    const float* fcb = (const float*)xpbuf + wave * 256;
    float s0 = 0.f, s1 = 0.f;
    #pragma unroll
    for (int j0 = 0; j0 < HID; j0 += 64) {
      float h = fcb[j0 + lane];
      s0 += h * W_fc[j0 + lane];
      s1 += h * W_fc[HID + j0 + lane];
    }
    #pragma unroll
    for (int off = 32; off > 0; off >>= 1) {
      s0 += __shfl_xor(s0, off, 64);
      s1 += __shfl_xor(s1, off, 64);
    }
    if (lane == 0) {
      const int b = g * 4 + wave;
      float l0 = s0 + b_fc[0], l1 = s1 + b_fc[1];
      float m = fmaxf(l0, l1);
      float lse = m + logf(expf(l0 - m) + expf(l1 - m));
      out[b*2 + 0] = l0 - lse;
      out[b*2 + 1] = l1 - lse;
    }
  }
}

extern "C" void kernel_launch(void* const* d_in, const int* in_sizes, int n_in,
                              void* d_out, int out_size, void* d_ws, size_t ws_size,
                              hipStream_t stream) {
  const float* x    = (const float*)d_in[0];
  const float* W_ih = (const float*)d_in[1];
  const float* W_hh = (const float*)d_in[2];
  const float* b_ih = (const float*)d_in[3];
  const float* b_hh = (const float*)d_in[4];
  const float* W_fc = (const float*)d_in[5];
  const float* b_fc = (const float*)d_in[6];
  float* out = (float*)d_out;

  const size_t wb_bytes = (size_t)256 * 320 * 2;   // 163,840
  if (ws_size < wb_bytes) return;
  unsigned short* w_bf = (unsigned short*)d_ws;

  hipLaunchKernelGGL(conv_wih, dim3(320), dim3(256), 0, stream, W_ih, w_bf);
  hipLaunchKernelGGL(rnn_all,  dim3(64),  dim3(512), 0, stream,
                     x, w_bf, b_ih, b_hh, W_hh, W_fc, b_fc, out);
}

// Round 9
// 528.322 us; speedup vs baseline: 1.0628x; 1.0033x over previous
//
#include <hip/hip_runtime.h>
#include <hip/hip_bf16.h>
#include <cstdint>
#include <cstddef>

#define SEQ 512
#define BATCH 256
#define IN_DIM 300
#define HID 256
#define XPROW 520          // xpbuf row stride (dwords); 520%32=8 -> quad-spread banks
#define ABUF  5248         // one a_lds buffer: 32 rows * 164 dwords

typedef __attribute__((ext_vector_type(8))) short bf16x8;
typedef __attribute__((ext_vector_type(4))) float f32x4;

__device__ __forceinline__ unsigned short f2bf(float f) {
  union { float f; unsigned int u; } v; v.f = f;
  unsigned int u = v.u;
  return (unsigned short)((u + 0x7fffu + ((u >> 16) & 1u)) >> 16);  // RNE
}
__device__ __forceinline__ unsigned short f2bf_fast(float f) {
  union { float f; unsigned int u; } v; v.f = f;
  return (unsigned short)((v.u + 0x8000u) >> 16);  // round-half-up
}
__device__ __forceinline__ float bitsf(unsigned int u) {
  union { unsigned int u; float f; } v; v.u = u; return v.f;
}
__device__ __forceinline__ unsigned int cvtpk(float lo, float hi) {
  union { __hip_bfloat162 h; unsigned int u; } c;
  c.h = __float22bfloat162_rn(make_float2(lo, hi));
  return c.u;
}
__device__ __forceinline__ bf16x8 cvt8(float a0,float a1,float a2,float a3,
                                       float a4,float a5,float a6,float a7) {
  union { __hip_bfloat162 h2[4]; bf16x8 v; } c;
  c.h2[0] = __float22bfloat162_rn(make_float2(a0, a1));
  c.h2[1] = __float22bfloat162_rn(make_float2(a2, a3));
  c.h2[2] = __float22bfloat162_rn(make_float2(a4, a5));
  c.h2[3] = __float22bfloat162_rn(make_float2(a6, a7));
  return c.v;
}
// LDS-drain-only workgroup barrier (global prefetches stay in flight).
__device__ __forceinline__ void barrier_lgkm() {
  asm volatile("s_waitcnt lgkmcnt(0)" ::: "memory");
  __builtin_amdgcn_s_barrier();
  asm volatile("" ::: "memory");
}

// ---------------- kernel 0: W_ih fp32 -> bf16, FRAGMENT-MAJOR (round-4).
// Short index: (((n16*10 + kc)*4 + quad)*16 + l15)*8 + j
__global__ __launch_bounds__(256) void conv_wih(const float* __restrict__ w,
                                                unsigned short* __restrict__ w_bf) {
  int idx = blockIdx.x * 256 + threadIdx.x;    // 0..81919
  int j    = idx & 7;
  int l15  = (idx >> 3) & 15;
  int quad = (idx >> 7) & 3;
  int t    = idx >> 9;
  int n16  = t / 10;
  int kc   = t - n16 * 10;
  int n = n16 * 16 + l15;
  int k = kc * 32 + quad * 8 + j;
  float v = (k < IN_DIM) ? w[n * IN_DIM + k] : 0.f;
  w_bf[idx] = f2bf(v);
}

// One GEMM chunk: kc, kc+1 (compile-time kc). Same per-acc kc order as the
// verified full win_gemm -> bit-identical accumulation.
__device__ __forceinline__ void gemm_chunk(const unsigned int* __restrict__ buf,
    f32x4 (&gacc)[2][2], const bf16x8 wfi[2][10], int kc, int l15, int quad)
{
  #pragma unroll
  for (int k2 = 0; k2 < 2; ++k2) {
    const int kk = kc + k2;
    bf16x8 afr0 = *(const bf16x8*)&buf[(     l15) * 164 + kk*16 + quad*4];
    bf16x8 afr1 = *(const bf16x8*)&buf[(16 + l15) * 164 + kk*16 + quad*4];
    gacc[0][0] = __builtin_amdgcn_mfma_f32_16x16x32_bf16(afr0, wfi[0][kk], gacc[0][0], 0, 0, 0);
    gacc[0][1] = __builtin_amdgcn_mfma_f32_16x16x32_bf16(afr0, wfi[1][kk], gacc[0][1], 0, 0, 0);
    gacc[1][0] = __builtin_amdgcn_mfma_f32_16x16x32_bf16(afr1, wfi[0][kk], gacc[1][0], 0, 0, 0);
    gacc[1][1] = __builtin_amdgcn_mfma_f32_16x16x32_bf16(afr1, wfi[1][kk], gacc[1][1], 0, 0, 0);
  }
}
// GEMM epilogue -> xp_wr rows (XPROW stride; same fmaf/cvtpk as verified).
__device__ __forceinline__ void gemm_epi(const f32x4 (&gacc)[2][2],
    unsigned int* __restrict__ xp_wr, float kb0, float kb1,
    int wave, int l15, int quad)
{
  #pragma unroll
  for (int nt = 0; nt < 2; ++nt) {
    const float kb = nt ? kb1 : kb0;
    const int tid_s = wave*64 + nt*16 + l15;
    #pragma unroll
    for (int mt = 0; mt < 2; ++mt) {
      const int idx = (mt*4 + quad) * XPROW + tid_s;   // t_loc = mt*4+quad
      float y0 = fmaf(2.0f, gacc[mt][nt][0], kb);
      float y1 = fmaf(2.0f, gacc[mt][nt][1], kb);
      float y2 = fmaf(2.0f, gacc[mt][nt][2], kb);
      float y3 = fmaf(2.0f, gacc[mt][nt][3], kb);
      xp_wr[idx]      = cvtpk(y0, y1);
      xp_wr[idx + 32] = cvtpk(y2, y3);
    }
  }
}

__device__ __forceinline__ void win_stage(unsigned int* __restrict__ buf,
    const float4* __restrict__ xr, const int* __restrict__ sidx, int tid)
{
  #pragma unroll
  for (int i = 0; i < 5; ++i)
    if (i < 4 || tid < 352) {
      uint2 pk2;
      pk2.x = cvtpk(xr[i].x, xr[i].y);
      pk2.y = cvtpk(xr[i].z, xr[i].w);
      *(uint2*)&buf[sidx[i]] = pk2;
    }
}

// ---------------- fused xp-GEMM + scan + FC, GEMM INTERLEAVED into scan steps.
// 64 blocks x 512 thr. During window W's 8 steps: gemm for window W+1 runs as
// 5 chunks (j=0..4) + epilogue (j=7), reading a_lds[(W+1)&1] (staged at j=5 of
// W-1) and writing xpbuf[(W+1)&1]. x for W+2 issued at j=0, staged at j=5.
// The chunk work (~160 cy/SIMD/step) fits in the scan's MFMA-chain stall slack
// -> GEMM ~free. All per-value math identical to verified kernels.
__global__ __launch_bounds__(512) void rnn_all(const float* __restrict__ x,
    const unsigned short* __restrict__ w_bf, const float* __restrict__ b_ih,
    const float* __restrict__ b_hh, const float* __restrict__ W_hh,
    const float* __restrict__ W_fc, const float* __restrict__ b_fc,
    float* __restrict__ out)
{
  __shared__ alignas(16) unsigned int   xpbuf[2 * 8 * XPROW];  // 33.3 KB
  __shared__ alignas(16) unsigned int   a_lds[2 * ABUF];       // 42 KB
  __shared__ alignas(16) unsigned short hbuf[2][1088];         // 4.3 KB

  const int tid  = threadIdx.x;
  const int wave = tid >> 6;
  const int lane = tid & 63;
  const int l15  = lane & 15;
  const int quad = lane >> 4;
  const int g    = blockIdx.x;
  const int c0   = wave * 32;

  // W_hh fragments (scan B), exact round-2 path
  bf16x8 wfh[2][8];
  #pragma unroll
  for (int nt = 0; nt < 2; ++nt) {
    const int n = c0 + nt*16 + l15;
    #pragma unroll
    for (int kc = 0; kc < 8; ++kc) {
      const float* src = W_hh + n*HID + kc*32 + quad*8;
      float4 p0 = *(const float4*)src;
      float4 p1 = *(const float4*)(src + 4);
      wfh[nt][kc] = cvt8(p0.x,p0.y,p0.z,p0.w,p1.x,p1.y,p1.z,p1.w);
    }
  }
  // W_ih fragments (xp B), fragment-major coalesced, in regs for the kernel
  bf16x8 wfi[2][10];
  #pragma unroll
  for (int nt = 0; nt < 2; ++nt) {
    const unsigned short* wp =
        w_bf + ((size_t)((wave*2 + nt)*10)*4 + quad)*128 + (size_t)l15*8;
    #pragma unroll
    for (int kc = 0; kc < 10; ++kc)
      wfi[nt][kc] = *(const bf16x8*)(wp + (size_t)kc*512);
  }
  const float kb0 = 2.0f * (b_ih[c0 + l15]      + b_hh[c0 + l15]);
  const float kb1 = 2.0f * (b_ih[c0 + 16 + l15] + b_hh[c0 + 16 + l15]);

  // per-thread x-load offsets: 5 float4 over 32 rows x 75 slots (2400 total)
  unsigned int voff[5]; int sidx[5];
  #pragma unroll
  for (int i = 0; i < 5; ++i) {
    const int e = tid + i * 512;
    const int row = e / 75;
    const int c4  = e - row * 75;
    const int t_loc = row >> 2, b_loc = row & 3;
    voff[i] = (unsigned)(((t_loc * 256 + 4 * g + b_loc) * 300 + c4 * 4) * 4);
    sidx[i] = row * 164 + c4 * 2;
  }

  const int rb    = (quad >> 1) * 2;
  const int col_e = c0 + (quad & 1) * 16 + l15;
  const int abase = (l15 & 3) * 272 + quad * 8;

  for (int i = tid; i < 1088; i += 512) hbuf[0][i] = 0;        // h0 = 0
  for (int i = tid; i < 640; i += 512) {                       // zero k=300..319, both bufs
    const int b   = i / 320;
    const int rem = i - b * 320;
    a_lds[b*ABUF + (rem/10)*164 + 150 + (rem%10)] = 0;
  }

  const size_t WSTRIDE = (size_t)8 * 256 * 300 * 4;            // bytes of x per window

  // ---- prologue: x0 -> buf0; gemm(0) -> xpbuf[0]; x1 -> buf1
  float4 xr[5];
  #pragma unroll
  for (int i = 0; i < 5; ++i)
    if (i < 4 || tid < 352)
      xr[i] = *(const float4*)((const char*)x + voff[i]);
  __syncthreads();
  win_stage(a_lds, xr, sidx, tid);                             // buf0 <- x0
  #pragma unroll
  for (int i = 0; i < 5; ++i)                                  // issue x1 early
    if (i < 4 || tid < 352)
      xr[i] = *(const float4*)((const char*)x + WSTRIDE + voff[i]);
  barrier_lgkm();
  {
    f32x4 gacc[2][2];
    gacc[0][0] = (f32x4){0.f,0.f,0.f,0.f}; gacc[0][1] = gacc[0][0];
    gacc[1][0] = gacc[0][0];               gacc[1][1] = gacc[0][0];
    #pragma unroll
    for (int kc = 0; kc < 10; kc += 2)
      gemm_chunk(a_lds, gacc, wfi, kc, l15, quad);
    gemm_epi(gacc, xpbuf, kb0, kb1, wave, l15, quad);
  }
  win_stage(a_lds + ABUF, xr, sidx, tid);                      // buf1 <- x1
  barrier_lgkm();

  // ---- main loop
  f32x4 gacc[2][2];
  for (int W = 0; W < 64; ++W) {
    const unsigned int* xp_rd = xpbuf + (W & 1) * (8 * XPROW);
    unsigned int*       xp_wr = xpbuf + ((W + 1) & 1) * (8 * XPROW);
    const unsigned int* gbuf  = a_lds + ((W + 1) & 1) * ABUF;  // x(W+1)
    unsigned int*       sbuf  = a_lds + (W & 1) * ABUF;        // <- x(W+2)
    const char* pn = (const char*)x + (size_t)(W + 2) * WSTRIDE;
    #pragma unroll
    for (int j = 0; j < 8; ++j) {
      if (j == 0 && W < 62) {                  // issue x(W+2)
        #pragma unroll
        for (int i = 0; i < 5; ++i)
          if (i < 4 || tid < 352)
            xr[i] = *(const float4*)(pn + voff[i]);
      }
      if (j == 0 && W < 63) {
        gacc[0][0] = (f32x4){0.f,0.f,0.f,0.f}; gacc[0][1] = gacc[0][0];
        gacc[1][0] = gacc[0][0];               gacc[1][1] = gacc[0][0];
      }
      const int cur = j & 1;                   // global parity = j&1 (8 even)
      const unsigned int xqj = xp_rd[j * XPROW + tid];
      bf16x8 afr[8];
      #pragma unroll
      for (int kc = 0; kc < 8; ++kc)
        afr[kc] = *(const bf16x8*)&hbuf[cur][abase + kc*32];
      f32x4 a0A = (f32x4){0.f,0.f,0.f,0.f}, a0B = a0A, a1A = a0A, a1B = a0A;
      #pragma unroll
      for (int kc = 0; kc < 8; kc += 2) {
        a0A = __builtin_amdgcn_mfma_f32_16x16x32_bf16(afr[kc],   wfh[0][kc],   a0A, 0, 0, 0);
        a1A = __builtin_amdgcn_mfma_f32_16x16x32_bf16(afr[kc],   wfh[1][kc],   a1A, 0, 0, 0);
        a0B = __builtin_amdgcn_mfma_f32_16x16x32_bf16(afr[kc+1], wfh[0][kc+1], a0B, 0, 0, 0);
        a1B = __builtin_amdgcn_mfma_f32_16x16x32_bf16(afr[kc+1], wfh[1][kc+1], a1B, 0, 0, 0);
      }
      if (j < 5 && W < 63)                     // gemm(W+1) chunk: kc=2j,2j+1
        gemm_chunk(gbuf, gacc, wfi, 2*j, l15, quad);
      if (j == 5 && W < 62)                    // stage x(W+2)
        win_stage(sbuf, xr, sidx, tid);
      f32x4 acc0 = a0A + a0B;
      f32x4 acc1 = a1A + a1B;
      f32x4 a = (quad & 1) ? acc1 : acc0;
      float s0 = (quad >> 1) ? a[2] : a[0];
      float s1 = (quad >> 1) ? a[3] : a[1];
      float xv0 = bitsf(xqj << 16);
      float xv1 = bitsf(xqj & 0xffff0000u);
      float y0 = fmaf(2.0f, s0, xv0);
      float y1 = fmaf(2.0f, s1, xv1);
      float h0 = fmaf(-2.0f, __builtin_amdgcn_rcpf(__expf(y0) + 1.0f), 1.0f);
      float h1 = fmaf(-2.0f, __builtin_amdgcn_rcpf(__expf(y1) + 1.0f), 1.0f);
      if (j == 7 && W < 63)                    // gemm(W+1) epilogue -> xp_wr
        gemm_epi(gacc, xp_wr, kb0, kb1, wave, l15, quad);
      if (W == 63 && j == 7) {                 // final h -> f32 LDS for FC
        float* fcb = (float*)xpbuf;            // = xp_wr region (unused at W=63)
        fcb[ rb      * 256 + col_e] = h0;
        fcb[(rb + 1) * 256 + col_e] = h1;
      } else {
        hbuf[1 - cur][ rb      * 272 + col_e] = f2bf_fast(h0);
        hbuf[1 - cur][(rb + 1) * 272 + col_e] = f2bf_fast(h1);
      }
      barrier_lgkm();
    }
  }

  // FC head: wave b_loc handles batch 4g+b_loc (same math as old fc_head)
  if (wave < 4) {
    const float* fcb = (const float*)xpbuf + wave * 256;
    float s0 = 0.f, s1 = 0.f;
    #pragma unroll
    for (int j0 = 0; j0 < HID; j0 += 64) {
      float h = fcb[j0 + lane];
      s0 += h * W_fc[j0 + lane];
      s1 += h * W_fc[HID + j0 + lane];
    }
    #pragma unroll
    for (int off = 32; off > 0; off >>= 1) {
      s0 += __shfl_xor(s0, off, 64);
      s1 += __shfl_xor(s1, off, 64);
    }
    if (lane == 0) {
      const int b = g * 4 + wave;
      float l0 = s0 + b_fc[0], l1 = s1 + b_fc[1];
      float m = fmaxf(l0, l1);
      float lse = m + logf(expf(l0 - m) + expf(l1 - m));
      out[b*2 + 0] = l0 - lse;
      out[b*2 + 1] = l1 - lse;
    }
  }
}

extern "C" void kernel_launch(void* const* d_in, const int* in_sizes, int n_in,
                              void* d_out, int out_size, void* d_ws, size_t ws_size,
                              hipStream_t stream) {
  const float* x    = (const float*)d_in[0];
  const float* W_ih = (const float*)d_in[1];
  const float* W_hh = (const float*)d_in[2];
  const float* b_ih = (const float*)d_in[3];
  const float* b_hh = (const float*)d_in[4];
  const float* W_fc = (const float*)d_in[5];
  const float* b_fc = (const float*)d_in[6];
  float* out = (float*)d_out;

  const size_t wb_bytes = (size_t)256 * 320 * 2;   // 163,840
  if (ws_size < wb_bytes) return;
  unsigned short* w_bf = (unsigned short*)d_ws;

  hipLaunchKernelGGL(conv_wih, dim3(320), dim3(256), 0, stream, W_ih, w_bf);
  hipLaunchKernelGGL(rnn_all,  dim3(64),  dim3(512), 0, stream,
                     x, w_bf, b_ih, b_hh, W_hh, W_fc, b_fc, out);
}

// Round 10
// 491.538 us; speedup vs baseline: 1.1424x; 1.0748x over previous
//
#include <hip/hip_runtime.h>
#include <hip/hip_bf16.h>
#include <cstdint>
#include <cstddef>

#define SEQ 512
#define BATCH 256
#define IN_DIM 300
#define HID 256

typedef __attribute__((ext_vector_type(8))) short bf16x8;
typedef __attribute__((ext_vector_type(4))) float f32x4;
typedef __attribute__((ext_vector_type(4))) unsigned int u32x4;

__device__ __forceinline__ unsigned short f2bf(float f) {
  union { float f; unsigned int u; } v; v.f = f;
  unsigned int u = v.u;
  return (unsigned short)((u + 0x7fffu + ((u >> 16) & 1u)) >> 16);  // RNE
}
__device__ __forceinline__ unsigned short f2bf_fast(float f) {
  union { float f; unsigned int u; } v; v.f = f;
  return (unsigned short)((v.u + 0x8000u) >> 16);  // round-half-up
}
__device__ __forceinline__ float bitsf(unsigned int u) {
  union { unsigned int u; float f; } v; v.u = u; return v.f;
}
__device__ __forceinline__ unsigned int cvtpk(float lo, float hi) {
  union { __hip_bfloat162 h; unsigned int u; } c;
  c.h = __float22bfloat162_rn(make_float2(lo, hi));
  return c.u;
}
__device__ __forceinline__ bf16x8 cvt8(float a0,float a1,float a2,float a3,
                                       float a4,float a5,float a6,float a7) {
  union { __hip_bfloat162 h2[4]; bf16x8 v; } c;
  c.h2[0] = __float22bfloat162_rn(make_float2(a0, a1));
  c.h2[1] = __float22bfloat162_rn(make_float2(a2, a3));
  c.h2[2] = __float22bfloat162_rn(make_float2(a4, a5));
  c.h2[3] = __float22bfloat162_rn(make_float2(a6, a7));
  return c.v;
}
// LDS-drain-only workgroup barrier (global prefetches stay in flight).
__device__ __forceinline__ void barrier_lgkm() {
  asm volatile("s_waitcnt lgkmcnt(0)" ::: "memory");
  __builtin_amdgcn_s_barrier();
  asm volatile("" ::: "memory");
}

struct F8 { float v[8]; };
__device__ __forceinline__ F8 load_x8(const float* __restrict__ xrow, int k0, int ac) {
  F8 r;
  if (k0 + ac + 8 <= IN_DIM) {
    float2 p0 = *(const float2*)(xrow + k0 + ac + 0);
    float2 p1 = *(const float2*)(xrow + k0 + ac + 2);
    float2 p2 = *(const float2*)(xrow + k0 + ac + 4);
    float2 p3 = *(const float2*)(xrow + k0 + ac + 6);
    r.v[0]=p0.x; r.v[1]=p0.y; r.v[2]=p1.x; r.v[3]=p1.y;
    r.v[4]=p2.x; r.v[5]=p2.y; r.v[6]=p3.x; r.v[7]=p3.y;
  } else {
    #pragma unroll
    for (int j = 0; j < 8; ++j)
      r.v[j] = (k0 + ac + j < IN_DIM) ? xrow[k0 + ac + j] : 0.f;
  }
  return r;
}

// ---------------- kernel 0: W_ih fp32 -> bf16, FRAGMENT-MAJOR (r4-exact).
__global__ __launch_bounds__(256) void conv_wih(const float* __restrict__ w,
                                                unsigned short* __restrict__ w_bf) {
  int idx = blockIdx.x * 256 + threadIdx.x;    // 0..81919
  int j    = idx & 7;
  int l15  = (idx >> 3) & 15;
  int quad = (idx >> 7) & 3;
  int t    = idx >> 9;
  int n16  = t / 10;
  int kc   = t - n16 * 10;
  int n = n16 * 16 + l15;
  int k = kc * 32 + quad * 8 + j;
  float v = (k < IN_DIM) ? w[n * IN_DIM + k] : 0.f;
  w_bf[idx] = f2bf(v);
}

// ---------------- kernel 1: xp2 GEMM (r4-exact; will be TOP dispatch next
// round -> first-ever counter row for this kernel).
__global__ __launch_bounds__(512, 2) void gemm_xp(const float* __restrict__ x,
    const unsigned short* __restrict__ w_bf, const float* __restrict__ b_ih,
    const float* __restrict__ b_hh, unsigned int* __restrict__ xp2)
{
  __shared__ unsigned int a_lds[2][128][20];
  const int tid  = threadIdx.x;
  const int wave = tid >> 6;
  const int lane = tid & 63;
  const int l15  = lane & 15;
  const int quad = lane >> 4;
  const long m0  = (long)blockIdx.x * 128;

  bf16x8 wf[2][10];
  #pragma unroll
  for (int nt = 0; nt < 2; ++nt) {
    const unsigned short* wp =
        w_bf + ((size_t)((wave*2 + nt)*10)*4 + quad)*16*8 + (size_t)l15*8;
    #pragma unroll
    for (int kc = 0; kc < 10; ++kc)
      wf[nt][kc] = *(const bf16x8*)(wp + (size_t)kc*4*16*8);
  }

  f32x4 acc[8][2];
  #pragma unroll
  for (int mt = 0; mt < 8; ++mt) {
    acc[mt][0] = (f32x4){0.f, 0.f, 0.f, 0.f};
    acc[mt][1] = (f32x4){0.f, 0.f, 0.f, 0.f};
  }

  const int ar = tid >> 2;
  const int ac = (tid & 3) * 8;
  const float* xrow = x + (size_t)(m0 + ar) * IN_DIM;

  F8 av[2];
  av[0] = load_x8(xrow, 0, ac);
  av[1] = load_x8(xrow, 32, ac);
  {
    u32x4 pk;
    pk.x = cvtpk(av[0].v[0], av[0].v[1]);
    pk.y = cvtpk(av[0].v[2], av[0].v[3]);
    pk.z = cvtpk(av[0].v[4], av[0].v[5]);
    pk.w = cvtpk(av[0].v[6], av[0].v[7]);
    *(u32x4*)&a_lds[0][ar][(tid & 3) * 4] = pk;
  }
  barrier_lgkm();

  #pragma unroll
  for (int kc = 0; kc < 10; ++kc) {
    const int cur = kc & 1;
    bf16x8 afr[8];
    #pragma unroll
    for (int mt = 0; mt < 8; ++mt)
      afr[mt] = *(const bf16x8*)&a_lds[cur][mt*16 + l15][quad*4];
    if (kc < 9) {
      const int s = (kc + 1) & 1;
      u32x4 pk;
      pk.x = cvtpk(av[s].v[0], av[s].v[1]);
      pk.y = cvtpk(av[s].v[2], av[s].v[3]);
      pk.z = cvtpk(av[s].v[4], av[s].v[5]);
      pk.w = cvtpk(av[s].v[6], av[s].v[7]);
      *(u32x4*)&a_lds[s][ar][(tid & 3) * 4] = pk;
    }
    if (kc < 8)
      av[kc & 1] = load_x8(xrow, (kc + 2) * 32, ac);
    #pragma unroll
    for (int mt = 0; mt < 8; ++mt) {
      acc[mt][0] = __builtin_amdgcn_mfma_f32_16x16x32_bf16(afr[mt], wf[0][kc], acc[mt][0], 0, 0, 0);
      acc[mt][1] = __builtin_amdgcn_mfma_f32_16x16x32_bf16(afr[mt], wf[1][kc], acc[mt][1], 0, 0, 0);
    }
    barrier_lgkm();
  }

  const int t  = (int)(blockIdx.x >> 1);
  const int b4 = ((int)blockIdx.x & 1) * 32;
  #pragma unroll
  for (int nt = 0; nt < 2; ++nt) {
    const int n = wave*32 + nt*16 + l15;
    const float kb = 2.0f * (b_ih[n] + b_hh[n]);
    const int tid_lo = wave*64 + nt*16 + l15;
    #pragma unroll
    for (int mt = 0; mt < 8; ++mt) {
      const int g = b4 + mt*4 + quad;
      const size_t base = ((size_t)t*64 + g) * 512;
      float y0 = fmaf(2.0f, acc[mt][nt][0], kb);
      float y1 = fmaf(2.0f, acc[mt][nt][1], kb);
      float y2 = fmaf(2.0f, acc[mt][nt][2], kb);
      float y3 = fmaf(2.0f, acc[mt][nt][3], kb);
      xp2[base + tid_lo]      = cvtpk(y0, y1);
      xp2[base + tid_lo + 32] = cvtpk(y2, y3);
    }
  }
}

// ---------------- scan PART A: steps 0..255 (r2-exact stepping). Always
// writes hbuf; final state (in hbuf[0], since step 255 writes buf 0) dumped
// to hmid as raw bf16 dwords -> bit-exact handoff.
__global__ __launch_bounds__(512) void rnn_scan_a(const float* __restrict__ W_hh,
    const unsigned int* __restrict__ xp2, unsigned int* __restrict__ hmid)
{
  __shared__ alignas(16) unsigned short hbuf[2][1088];
  const int tid  = threadIdx.x;
  const int wave = tid >> 6;
  const int lane = tid & 63;
  const int l15  = lane & 15;
  const int quad = lane >> 4;
  const int g = blockIdx.x;
  const int c0 = wave * 32;

  bf16x8 wf[2][8];
  #pragma unroll
  for (int nt = 0; nt < 2; ++nt) {
    const int n = c0 + nt*16 + l15;
    #pragma unroll
    for (int kc = 0; kc < 8; ++kc) {
      const float* src = W_hh + n*HID + kc*32 + quad*8;
      float4 p0 = *(const float4*)src;
      float4 p1 = *(const float4*)(src + 4);
      wf[nt][kc] = cvt8(p0.x,p0.y,p0.z,p0.w,p1.x,p1.y,p1.z,p1.w);
    }
  }

  const int rb    = (quad >> 1) * 2;
  const int col_e = c0 + (quad & 1) * 16 + l15;
  const int abase = (l15 & 3) * 272 + quad * 8;

  for (int i = tid; i < 1088; i += 512) hbuf[0][i] = 0;

  const unsigned int* xbase = xp2 + (size_t)g * 512 + tid;

  __syncthreads();

  unsigned int xq[16], xqn[16];
  #pragma unroll
  for (int j = 0; j < 16; ++j)
    xq[j] = xbase[(size_t)j * 32768];

  for (int tc = 0; tc < 16; ++tc) {
    if (tc < 15) {
      const unsigned int* pn = xbase + (size_t)(tc + 1) * 16 * 32768;
      #pragma unroll
      for (int j = 0; j < 16; ++j)
        xqn[j] = pn[(size_t)j * 32768];
    }
    #pragma unroll
    for (int j = 0; j < 16; ++j) {
      const int cur = j & 1;
      bf16x8 afr[8];
      #pragma unroll
      for (int kc = 0; kc < 8; ++kc)
        afr[kc] = *(const bf16x8*)&hbuf[cur][abase + kc*32];
      f32x4 a0A = (f32x4){0.f,0.f,0.f,0.f}, a0B = a0A, a1A = a0A, a1B = a0A;
      #pragma unroll
      for (int kc = 0; kc < 8; kc += 2) {
        a0A = __builtin_amdgcn_mfma_f32_16x16x32_bf16(afr[kc],   wf[0][kc],   a0A, 0, 0, 0);
        a1A = __builtin_amdgcn_mfma_f32_16x16x32_bf16(afr[kc],   wf[1][kc],   a1A, 0, 0, 0);
        a0B = __builtin_amdgcn_mfma_f32_16x16x32_bf16(afr[kc+1], wf[0][kc+1], a0B, 0, 0, 0);
        a1B = __builtin_amdgcn_mfma_f32_16x16x32_bf16(afr[kc+1], wf[1][kc+1], a1B, 0, 0, 0);
      }
      f32x4 acc0 = a0A + a0B;
      f32x4 acc1 = a1A + a1B;
      f32x4 a = (quad & 1) ? acc1 : acc0;
      float s0 = (quad >> 1) ? a[2] : a[0];
      float s1 = (quad >> 1) ? a[3] : a[1];
      float xv0 = bitsf(xq[j] << 16);
      float xv1 = bitsf(xq[j] & 0xffff0000u);
      float y0 = fmaf(2.0f, s0, xv0);
      float y1 = fmaf(2.0f, s1, xv1);
      float h0 = fmaf(-2.0f, __builtin_amdgcn_rcpf(__expf(y0) + 1.0f), 1.0f);
      float h1 = fmaf(-2.0f, __builtin_amdgcn_rcpf(__expf(y1) + 1.0f), 1.0f);
      hbuf[1 - cur][ rb      * 272 + col_e] = f2bf_fast(h0);
      hbuf[1 - cur][(rb + 1) * 272 + col_e] = f2bf_fast(h1);
      barrier_lgkm();
    }
    if (tc < 15) {
      #pragma unroll
      for (int j = 0; j < 16; ++j)
        xq[j] = xqn[j];
    }
  }
  // dump state (step 255 wrote hbuf[0]); last barrier already ordered writes
  const unsigned int* hb0 = (const unsigned int*)&hbuf[0][0];
  for (int i = tid; i < 544; i += 512)
    hmid[(size_t)g * 544 + i] = hb0[i];
}

// ---------------- scan PART B: steps 256..511. Loads exact bf16 state into
// hbuf[0] (global step 256 has parity 0 -> reads hbuf[0], matching part A's
// final write). Final step writes hT.
__global__ __launch_bounds__(512) void rnn_scan_b(const float* __restrict__ W_hh,
    const unsigned int* __restrict__ xp2, const unsigned int* __restrict__ hmid,
    float* __restrict__ hT)
{
  __shared__ alignas(16) unsigned short hbuf[2][1088];
  const int tid  = threadIdx.x;
  const int wave = tid >> 6;
  const int lane = tid & 63;
  const int l15  = lane & 15;
  const int quad = lane >> 4;
  const int g = blockIdx.x;
  const int c0 = wave * 32;

  bf16x8 wf[2][8];
  #pragma unroll
  for (int nt = 0; nt < 2; ++nt) {
    const int n = c0 + nt*16 + l15;
    #pragma unroll
    for (int kc = 0; kc < 8; ++kc) {
      const float* src = W_hh + n*HID + kc*32 + quad*8;
      float4 p0 = *(const float4*)src;
      float4 p1 = *(const float4*)(src + 4);
      wf[nt][kc] = cvt8(p0.x,p0.y,p0.z,p0.w,p1.x,p1.y,p1.z,p1.w);
    }
  }

  const int rb    = (quad >> 1) * 2;
  const int col_e = c0 + (quad & 1) * 16 + l15;
  const int abase = (l15 & 3) * 272 + quad * 8;

  {
    unsigned int* hb0 = (unsigned int*)&hbuf[0][0];
    for (int i = tid; i < 544; i += 512)
      hb0[i] = hmid[(size_t)g * 544 + i];
  }

  const unsigned int* xbase = xp2 + (size_t)g * 512 + tid;

  __syncthreads();

  unsigned int xq[16], xqn[16];
  #pragma unroll
  for (int j = 0; j < 16; ++j)
    xq[j] = xbase[(size_t)(256 + j) * 32768];

  for (int tc2 = 0; tc2 < 16; ++tc2) {
    if (tc2 < 15) {
      const unsigned int* pn = xbase + (size_t)(17 + tc2) * 16 * 32768;
      #pragma unroll
      for (int j = 0; j < 16; ++j)
        xqn[j] = pn[(size_t)j * 32768];
    }
    #pragma unroll
    for (int j = 0; j < 16; ++j) {
      const int cur = j & 1;                 // global parity == j&1 (256 even)
      bf16x8 afr[8];
      #pragma unroll
      for (int kc = 0; kc < 8; ++kc)
        afr[kc] = *(const bf16x8*)&hbuf[cur][abase + kc*32];
      f32x4 a0A = (f32x4){0.f,0.f,0.f,0.f}, a0B = a0A, a1A = a0A, a1B = a0A;
      #pragma unroll
      for (int kc = 0; kc < 8; kc += 2) {
        a0A = __builtin_amdgcn_mfma_f32_16x16x32_bf16(afr[kc],   wf[0][kc],   a0A, 0, 0, 0);
        a1A = __builtin_amdgcn_mfma_f32_16x16x32_bf16(afr[kc],   wf[1][kc],   a1A, 0, 0, 0);
        a0B = __builtin_amdgcn_mfma_f32_16x16x32_bf16(afr[kc+1], wf[0][kc+1], a0B, 0, 0, 0);
        a1B = __builtin_amdgcn_mfma_f32_16x16x32_bf16(afr[kc+1], wf[1][kc+1], a1B, 0, 0, 0);
      }
      f32x4 acc0 = a0A + a0B;
      f32x4 acc1 = a1A + a1B;
      f32x4 a = (quad & 1) ? acc1 : acc0;
      float s0 = (quad >> 1) ? a[2] : a[0];
      float s1 = (quad >> 1) ? a[3] : a[1];
      float xv0 = bitsf(xq[j] << 16);
      float xv1 = bitsf(xq[j] & 0xffff0000u);
      float y0 = fmaf(2.0f, s0, xv0);
      float y1 = fmaf(2.0f, s1, xv1);
      float h0 = fmaf(-2.0f, __builtin_amdgcn_rcpf(__expf(y0) + 1.0f), 1.0f);
      float h1 = fmaf(-2.0f, __builtin_amdgcn_rcpf(__expf(y1) + 1.0f), 1.0f);
      if (j < 15 || tc2 < 15) {
        hbuf[1 - cur][ rb      * 272 + col_e] = f2bf_fast(h0);
        hbuf[1 - cur][(rb + 1) * 272 + col_e] = f2bf_fast(h1);
      } else {
        hT[(size_t)(g*4 + rb    ) * HID + col_e] = h0;
        hT[(size_t)(g*4 + rb + 1) * HID + col_e] = h1;
      }
      barrier_lgkm();
    }
    if (tc2 < 15) {
      #pragma unroll
      for (int j = 0; j < 16; ++j)
        xq[j] = xqn[j];
    }
  }
}

// ---------------- kernel 3: logits + log_softmax (r4-exact).
__global__ __launch_bounds__(64) void fc_head(const float* __restrict__ hT,
    const float* __restrict__ W_fc, const float* __restrict__ b_fc,
    float* __restrict__ out)
{
  const int b = blockIdx.x;
  const int l = threadIdx.x;
  float s0 = 0.f, s1 = 0.f;
  #pragma unroll
  for (int j0 = 0; j0 < HID; j0 += 64) {
    float h = hT[(size_t)b * HID + j0 + l];
    s0 += h * W_fc[j0 + l];
    s1 += h * W_fc[HID + j0 + l];
  }
  #pragma unroll
  for (int off = 32; off > 0; off >>= 1) {
    s0 += __shfl_xor(s0, off, 64);
    s1 += __shfl_xor(s1, off, 64);
  }
  if (l == 0) {
    float l0 = s0 + b_fc[0], l1 = s1 + b_fc[1];
    float m = fmaxf(l0, l1);
    float lse = m + logf(expf(l0 - m) + expf(l1 - m));
    out[b*2 + 0] = l0 - lse;
    out[b*2 + 1] = l1 - lse;
  }
}

extern "C" void kernel_launch(void* const* d_in, const int* in_sizes, int n_in,
                              void* d_out, int out_size, void* d_ws, size_t ws_size,
                              hipStream_t stream) {
  const float* x    = (const float*)d_in[0];
  const float* W_ih = (const float*)d_in[1];
  const float* W_hh = (const float*)d_in[2];
  const float* b_ih = (const float*)d_in[3];
  const float* b_hh = (const float*)d_in[4];
  const float* W_fc = (const float*)d_in[5];
  const float* b_fc = (const float*)d_in[6];
  float* out = (float*)d_out;

  const size_t xp_bytes = (size_t)SEQ * BATCH * HID * 2;   // 67,108,864
  const size_t wb_bytes = (size_t)256 * 320 * 2;           // 163,840
  const size_t ht_bytes = (size_t)BATCH * HID * 4;         // 262,144
  const size_t hm_bytes = (size_t)64 * 544 * 4;            // 139,264
  if (ws_size < xp_bytes + wb_bytes + ht_bytes + hm_bytes) return;

  char* ws = (char*)d_ws;
  unsigned int*   xp2  = (unsigned int*)ws;
  unsigned short* w_bf = (unsigned short*)(ws + xp_bytes);
  float*          hT   = (float*)(ws + xp_bytes + wb_bytes);
  unsigned int*   hmid = (unsigned int*)(ws + xp_bytes + wb_bytes + ht_bytes);

  hipLaunchKernelGGL(conv_wih,   dim3(320),   dim3(256), 0, stream, W_ih, w_bf);
  hipLaunchKernelGGL(gemm_xp,    dim3(1024),  dim3(512), 0, stream, x, w_bf, b_ih, b_hh, xp2);
  hipLaunchKernelGGL(rnn_scan_a, dim3(64),    dim3(512), 0, stream, W_hh, xp2, hmid);
  hipLaunchKernelGGL(rnn_scan_b, dim3(64),    dim3(512), 0, stream, W_hh, xp2, hmid, hT);
  hipLaunchKernelGGL(fc_head,    dim3(BATCH), dim3(64),  0, stream, hT, W_fc, b_fc, out);
}